// Round 3
// baseline (923.983 us; speedup 1.0000x reference)
//
#include <hip/hip_runtime.h>
#include <math.h>

// MomentLayerRecurrent — round 3.
// vs round 2: (1) diag(C) computed in GEMM1 epilogue from fp32 accumulators
// (atomicAdd into s_var) — removes k_dots' 33.5MB/step T1 re-read and improves
// s_lin precision; (2) k_tables split into parallel k_exp + LDS-staged k_scan;
// (3) XCD-aware block swizzle so blocks sharing a B-operand tile are congruent
// mod 8 (same XCD L2); (4) k_stats+k_act fused into k_bnact (also zeroes s_var).

#define BB 32
#define NN 512
#define SEQ 8
#define TG 7001

typedef float f32x4 __attribute__((ext_vector_type(4)));
typedef short s16x8 __attribute__((ext_vector_type(8)));

#define GL16(g, l) __builtin_amdgcn_global_load_lds( \
    (const __attribute__((address_space(1))) void*)(g), \
    (__attribute__((address_space(3))) void*)(l), 16, 0, 0)

__device__ __forceinline__ unsigned short bf16_rne(float v) {
    unsigned u = __float_as_uint(v);
    u += 0x7FFFu + ((u >> 16) & 1u);
    return (unsigned short)(u >> 16);
}
__device__ __forceinline__ float bf16_f(unsigned short h) {
    return __uint_as_float(((unsigned)h) << 16);
}
__device__ __forceinline__ void split2(float v, unsigned short& h, unsigned short& l) {
    unsigned short hh = bf16_rne(v);
    h = hh;
    l = bf16_rne(v - bf16_f(hh));
}

__device__ __forceinline__ float interp_tab(const float* __restrict__ tab, float x) {
    float t = (x + 10.0f) * 500.0f;
    t = fminf(fmaxf(t, 0.0f), 7000.0f);
    int i0 = (int)t;
    if (i0 > 6999) i0 = 6999;
    float fr = t - (float)i0;
    float a = tab[i0];
    float b = tab[i0 + 1];
    return a + fr * (b - a);
}

// ---------------- exp precompute (parallel) ----------------------------------
__global__ void k_exp(double* __restrict__ expP, double* __restrict__ expM) {
    int k = blockIdx.x * 256 + threadIdx.x;
    if (k >= TG) return;
    double x = -10.0 + (14.0 / 7000.0) * k;
    expP[k] = exp(x * x);
    expM[k] = exp(-x * x);
}

// ---------------- chained cumtrapz scans, y staged in LDS --------------------
__device__ double blk_exscan(double part, double* wsum) {
    int t = threadIdx.x, lane = t & 63, wid = t >> 6;
    double run = part;
    #pragma unroll
    for (int off = 1; off < 64; off <<= 1) {
        double nv = __shfl_up(run, off);
        if (lane >= off) run += nv;
    }
    if (lane == 63) wsum[wid] = run;
    __syncthreads();
    if (t < 16) {
        double v = wsum[t];
        #pragma unroll
        for (int off = 1; off < 16; off <<= 1) {
            double nv = __shfl_up(v, off);
            if (lane >= off) v += nv;
        }
        wsum[t] = v;
    }
    __syncthreads();
    double base = (wid > 0) ? wsum[wid - 1] : 0.0;
    double ex = base + run - part;
    __syncthreads();
    return ex;
}

__global__ __launch_bounds__(1024)
void k_scan(const double* __restrict__ expP, const double* __restrict__ expM,
            float* __restrict__ GT, float* __restrict__ GI, float* __restrict__ HI) {
    __shared__ double ys[7008];
    __shared__ double wsum[16];
    const int t = threadIdx.x;
    const double dx = 14.0 / 7000.0;
    int k0 = t * 7, k1 = k0 + 7;
    if (k1 > TG) k1 = TG;
    if (k0 > TG) k0 = TG;
    int kls = (k0 < 1) ? 1 : k0;

    for (int k = k0; k < k1; ++k) ys[k] = expM[k];
    __syncthreads();

    double tmp[7];
    // phase 1: I = exp(-100)/20 + cumtrapz(expM); g = expP*I
    {
        double part = 0.0;
        for (int k = kls; k < k1; ++k) part += 0.5 * (ys[k - 1] + ys[k]) * dx;
        double run = blk_exscan(part, wsum) + exp(-100.0) / 20.0;
        int c = 0;
        for (int k = k0; k < k1; ++k) {
            if (k >= 1) run += 0.5 * (ys[k - 1] + ys[k]) * dx;
            tmp[c] = expP[k] * run;
            GT[k] = (float)tmp[c];
            ++c;
        }
        __syncthreads();
        c = 0;
        for (int k = k0; k < k1; ++k) ys[k] = tmp[c++];
        __syncthreads();
    }
    // phase 2: G = cumtrapz(g)   (ys = g, preserved)
    {
        double part = 0.0;
        for (int k = kls; k < k1; ++k) part += 0.5 * (ys[k - 1] + ys[k]) * dx;
        double run = blk_exscan(part, wsum);
        for (int k = k0; k < k1; ++k) {
            if (k >= 1) run += 0.5 * (ys[k - 1] + ys[k]) * dx;
            GI[k] = (float)run;
        }
        __syncthreads();
    }
    // phase 3: E = cumtrapz(expM * g^2)
    {
        double part = 0.0;
        for (int k = kls; k < k1; ++k) {
            double ya = expM[k - 1] * ys[k - 1] * ys[k - 1];
            double yb = expM[k] * ys[k] * ys[k];
            part += 0.5 * (ya + yb) * dx;
        }
        double run = blk_exscan(part, wsum);
        int c = 0;
        for (int k = k0; k < k1; ++k) {
            if (k >= 1) {
                double ya = expM[k - 1] * ys[k - 1] * ys[k - 1];
                double yb = expM[k] * ys[k] * ys[k];
                run += 0.5 * (ya + yb) * dx;
            }
            tmp[c++] = run;
        }
        __syncthreads();
        c = 0;
        for (int k = k0; k < k1; ++k) ys[k] = tmp[c++];
        __syncthreads();
    }
    // phase 4: H = cumtrapz(expP * E)   (ys = E)
    {
        double part = 0.0;
        for (int k = kls; k < k1; ++k)
            part += 0.5 * (expP[k - 1] * ys[k - 1] + expP[k] * ys[k]) * dx;
        double run = blk_exscan(part, wsum);
        for (int k = k0; k < k1; ++k) {
            if (k >= 1) run += 0.5 * (expP[k - 1] * ys[k - 1] + expP[k] * ys[k]) * dx;
            HI[k] = (float)run;
        }
    }
}

// ---------------- split kernels ----------------------------------------------
__global__ void k_splitW(const float* __restrict__ W,
                         unsigned short* __restrict__ Wh, unsigned short* __restrict__ Wl) {
    int idx = blockIdx.x * 256 + threadIdx.x;
    unsigned short h, l;
    split2(W[idx], h, l);
    Wh[idx] = h; Wl[idx] = l;
}

__global__ void k_splitQ(const float* __restrict__ rho, const float* __restrict__ s,
                         unsigned short* __restrict__ Qh, unsigned short* __restrict__ Ql) {
    size_t idx = (size_t)blockIdx.x * 256 + threadIdx.x;
    int b = (int)(idx >> 18);
    int i = (int)((idx >> 9) & 511);
    int j = (int)(idx & 511);
    float v = rho[idx] * s[b * NN + i] * s[b * NN + j];
    unsigned short h, l;
    split2(v, h, l);
    Qh[idx] = h; Ql[idx] = l;
}

// ---------------- MFMA GEMM: 128x128 tile, BK=32, split-2 bf16 ---------------
// 1-D grid of 512 blocks, XCD swizzle: blocks sharing a B tile (SWZ=0: same
// (x,z) varying y; SWZ=1: same (y,z) varying x) are congruent mod 8.
// MODE 0: write C split-bf16 to Oh/Ol + diag(C@W^T) partials into s_var.
// MODE 1: rho epilogue, write Q_next split-bf16.  MODE 2: fp32 rho to Of.
template <int MODE, int SWZ>
__global__ __launch_bounds__(256)
void gemm_mfma(const unsigned short* __restrict__ Ah, const unsigned short* __restrict__ Al,
               long aStride,
               const unsigned short* __restrict__ Bh, const unsigned short* __restrict__ Bl,
               long bStride,
               unsigned short* __restrict__ Oh, unsigned short* __restrict__ Ol,
               float* __restrict__ Of,
               const float* __restrict__ Wf, float* __restrict__ s_var,
               const float* __restrict__ s_lin, const float* __restrict__ chi,
               const float* __restrict__ s_next) {
    __shared__ __align__(16) unsigned short As0[4096], As1[4096], Bs0[4096], Bs1[4096];
    const int id = blockIdx.x;
    const int member = (id >> 3) & 3;
    const int g = (id & 7) | ((id >> 5) << 3);     // 0..127
    const int p = g & 3;
    const int b = g >> 2;
    const int xt = (SWZ == 0) ? p : member;
    const int yt = (SWZ == 0) ? member : p;
    const int i0 = yt * 128, j0 = xt * 128;
    const int tid = threadIdx.x;
    const int w = tid >> 6, lane = tid & 63;
    const int wm = w >> 1, wn = w & 1;

    const unsigned short* Ab_h = Ah + (size_t)b * aStride;
    const unsigned short* Ab_l = Al + (size_t)b * aStride;
    const unsigned short* Bb_h = Bh + (size_t)b * bStride;
    const unsigned short* Bb_l = Bl + (size_t)b * bStride;

    const size_t gA0 = ((size_t)(i0 + (w * 2 + 0) * 16 + (lane >> 2)) << 9) + ((lane & 3) << 3);
    const size_t gA1 = ((size_t)(i0 + (w * 2 + 1) * 16 + (lane >> 2)) << 9) + ((lane & 3) << 3);
    const size_t gB0 = ((size_t)(j0 + (w * 2 + 0) * 16 + (lane >> 2)) << 9) + ((lane & 3) << 3);
    const size_t gB1 = ((size_t)(j0 + (w * 2 + 1) * 16 + (lane >> 2)) << 9) + ((lane & 3) << 3);
    const int lds0 = (w * 2 + 0) * 512;
    const int lds1 = (w * 2 + 1) * 512;

    f32x4 acc[4][4];
    #pragma unroll
    for (int m = 0; m < 4; ++m)
        #pragma unroll
        for (int n = 0; n < 4; ++n) acc[m][n] = (f32x4){0.f, 0.f, 0.f, 0.f};

    const int kg = lane >> 4;
    int aoff[4], boff[4];
    #pragma unroll
    for (int t = 0; t < 4; ++t) {
        aoff[t] = (wm * 64 + t * 16 + (lane & 15)) * 32 + kg * 8;
        boff[t] = (wn * 64 + t * 16 + (lane & 15)) * 32 + kg * 8;
    }

    for (int k0 = 0; k0 < NN; k0 += 32) {
        GL16(Ab_h + gA0 + k0, As0 + lds0);
        GL16(Ab_h + gA1 + k0, As0 + lds1);
        GL16(Ab_l + gA0 + k0, As1 + lds0);
        GL16(Ab_l + gA1 + k0, As1 + lds1);
        GL16(Bb_h + gB0 + k0, Bs0 + lds0);
        GL16(Bb_h + gB1 + k0, Bs0 + lds1);
        GL16(Bb_l + gB0 + k0, Bs1 + lds0);
        GL16(Bb_l + gB1 + k0, Bs1 + lds1);
        __syncthreads();
        s16x8 ah[4], al[4], bh[4], bl[4];
        #pragma unroll
        for (int t = 0; t < 4; ++t) {
            ah[t] = *reinterpret_cast<const s16x8*>(&As0[aoff[t]]);
            al[t] = *reinterpret_cast<const s16x8*>(&As1[aoff[t]]);
            bh[t] = *reinterpret_cast<const s16x8*>(&Bs0[boff[t]]);
            bl[t] = *reinterpret_cast<const s16x8*>(&Bs1[boff[t]]);
        }
        #pragma unroll
        for (int m = 0; m < 4; ++m)
            #pragma unroll
            for (int n = 0; n < 4; ++n) {
                acc[m][n] = __builtin_amdgcn_mfma_f32_16x16x32_bf16(ah[m], bh[n], acc[m][n], 0, 0, 0);
                acc[m][n] = __builtin_amdgcn_mfma_f32_16x16x32_bf16(ah[m], bl[n], acc[m][n], 0, 0, 0);
                acc[m][n] = __builtin_amdgcn_mfma_f32_16x16x32_bf16(al[m], bh[n], acc[m][n], 0, 0, 0);
            }
        __syncthreads();
    }

    // epilogue — C/D layout: col = lane&15, row = (lane>>4)*4 + reg
    const size_t bofs = (size_t)b * NN * NN;
    const int rb = i0 + wm * 64 + (lane >> 4) * 4;
    const int cb = j0 + wn * 64 + (lane & 15);

    if (MODE == 0) {
        // diag partials: dp[m*4+r] = sum_n acc[m][n][r] * W[row, col_n]
        float dp[16];
        #pragma unroll
        for (int m = 0; m < 4; ++m)
            #pragma unroll
            for (int r = 0; r < 4; ++r) {
                int row = rb + m * 16 + r;
                const float* wrow = Wf + ((size_t)row << 9) + cb;
                float s = 0.0f;
                #pragma unroll
                for (int n = 0; n < 4; ++n) s = fmaf(acc[m][n][r], wrow[n * 16], s);
                dp[m * 4 + r] = s;
            }
        #pragma unroll
        for (int k = 0; k < 16; ++k) {
            #pragma unroll
            for (int off = 1; off < 16; off <<= 1) dp[k] += __shfl_xor(dp[k], off);
        }
        if ((lane & 15) == 0) {
            #pragma unroll
            for (int k = 0; k < 16; ++k) {
                int row = rb + (k >> 2) * 16 + (k & 3);
                atomicAdd(&s_var[b * NN + row], dp[k]);
            }
        }
        // store T1 split
        #pragma unroll
        for (int m = 0; m < 4; ++m)
            #pragma unroll
            for (int n = 0; n < 4; ++n) {
                int col = cb + n * 16;
                #pragma unroll
                for (int r = 0; r < 4; ++r) {
                    int row = rb + m * 16 + r;
                    size_t idx = bofs + ((size_t)row << 9) + col;
                    unsigned short h, l;
                    split2(acc[m][n][r], h, l);
                    Oh[idx] = h; Ol[idx] = l;
                }
            }
    } else {
        const float* sl = s_lin + b * NN;
        const float* ch = chi + b * NN;
        float sj[4], cj[4], qj[4];
        #pragma unroll
        for (int n = 0; n < 4; ++n) {
            int col = cb + n * 16;
            sj[n] = sl[col];
            cj[n] = ch[col];
            if (MODE == 1) qj[n] = s_next[b * NN + col];
        }
        #pragma unroll
        for (int m = 0; m < 4; ++m)
            #pragma unroll
            for (int r = 0; r < 4; ++r) {
                int row = rb + m * 16 + r;
                float si = sl[row], ci = ch[row];
                float qi = (MODE == 1) ? s_next[b * NN + row] : 0.f;
                #pragma unroll
                for (int n = 0; n < 4; ++n) {
                    int col = cb + n * 16;
                    float denom = si * sj[n];
                    float rv = (denom > 1e-12f) ? (acc[m][n][r] / fmaxf(denom, 1e-12f)) : 0.0f;
                    rv *= ci * cj[n];
                    if (row == col) rv = 1.0f;
                    size_t idx = bofs + ((size_t)row << 9) + col;
                    if (MODE == 1) {
                        unsigned short h, l;
                        split2(rv * qi * qj[n], h, l);
                        Oh[idx] = h; Ol[idx] = l;
                    } else {
                        Of[idx] = rv;
                    }
                }
            }
    }
}

// ---------------- external pathway -------------------------------------------
__global__ void k_ext_dots(const float* __restrict__ Wx, const float* __restrict__ bx,
                           const float* __restrict__ ux, const float* __restrict__ sx,
                           float* __restrict__ u_e, float* __restrict__ s_e2) {
    int gw = (blockIdx.x << 2) + (threadIdx.x >> 6);
    int lane = threadIdx.x & 63;
    int b = gw >> 9, i = gw & 511;
    const float* wr = Wx + (size_t)i * NN;
    const float* ub = ux + b * NN;
    const float* sb = sx + b * NN;
    float au = 0.0f, as2 = 0.0f;
    for (int j = lane; j < NN; j += 64) {
        float w = wr[j];
        float s = sb[j];
        au = fmaf(w, ub[j], au);
        as2 = fmaf(w * w, s * s, as2);
    }
    #pragma unroll
    for (int off = 32; off; off >>= 1) {
        au += __shfl_down(au, off);
        as2 += __shfl_down(as2, off);
    }
    if (lane == 0) {
        u_e[b * NN + i] = au + bx[i];
        s_e2[b * NN + i] = as2;
    }
}

__global__ void k_ext_stats(float* __restrict__ u_e, float* __restrict__ s_e2,
                            const float* __restrict__ wmx, const float* __restrict__ bmx) {
    int i = blockIdx.x * blockDim.x + threadIdx.x;
    if (i >= NN) return;
    float m = 0.0f;
    for (int b = 0; b < BB; ++b) m += u_e[b * NN + i];
    m *= (1.0f / BB);
    float v = 0.0f;
    for (int b = 0; b < BB; ++b) {
        float d = u_e[b * NN + i] - m;
        v = fmaf(d, d, v);
    }
    v *= (1.0f / BB);
    float f = wmx[i] / sqrtf(v + 1e-5f);
    float bm = bmx[i];
    for (int b = 0; b < BB; ++b) {
        u_e[b * NN + i] = (u_e[b * NN + i] - m) * f + bm;
        s_e2[b * NN + i] *= f * f;
    }
}

// ---------------- u_lin = u @ W^T + b (wave per (b,i)) -----------------------
__global__ void k_gemv(const float* __restrict__ W, const float* __restrict__ bvec,
                       const float* __restrict__ u, float* __restrict__ u_lin) {
    int gw = (blockIdx.x << 2) + (threadIdx.x >> 6);
    int lane = threadIdx.x & 63;
    int b = gw >> 9, i = gw & 511;
    const float* wr = W + (size_t)i * NN;
    const float* ub = u + b * NN;
    float au = 0.0f;
    for (int j = lane; j < NN; j += 64)
        au = fmaf(wr[j], ub[j], au);
    #pragma unroll
    for (int off = 32; off; off >>= 1)
        au += __shfl_down(au, off);
    if (lane == 0)
        u_lin[b * NN + i] = au + bvec[i];
}

// ---------------- BN stats + BN apply + ext merge + activation ---------------
__global__ void k_bnact(const float* __restrict__ u_lin, float* __restrict__ s_var,
                        const float* __restrict__ wm, const float* __restrict__ bmv,
                        const float* __restrict__ u_e, const float* __restrict__ s_e2,
                        const float* __restrict__ GT, const float* __restrict__ GI,
                        const float* __restrict__ HI,
                        float* __restrict__ u_out, float* __restrict__ s_out,
                        float* __restrict__ chi, float* __restrict__ s_lin) {
    int i = blockIdx.x * 256 + threadIdx.x;   // 0..511
    const float SQL = 0.22360679774997896f;
    float m = 0.0f;
    for (int b = 0; b < BB; ++b) m += u_lin[b * NN + i];
    m *= (1.0f / BB);
    float v = 0.0f;
    for (int b = 0; b < BB; ++b) {
        float d = u_lin[b * NN + i] - m;
        v = fmaf(d, d, v);
    }
    v *= (1.0f / BB);
    float f = wm[i] / sqrtf(v + 1e-5f);
    float bm = bmv[i];
    for (int b = 0; b < BB; ++b) {
        int idx = b * NN + i;
        float sv = s_var[idx];
        s_var[idx] = 0.0f;                     // zero for next step's atomics
        float s_l = sqrtf(fmaxf(sv, 0.0f));
        s_lin[idx] = s_l;
        float un = (u_lin[idx] - m) * f + bm + u_e[idx];
        float sn = sqrtf(s_l * s_l * f * f + s_e2[idx]);
        float ss = fmaxf(sn, 1e-6f);
        float inv = 1.0f / (ss * SQL);
        float ubx = fminf(fmaxf((1.0f - un) * inv, -10.0f), 4.0f);
        float lbx = fminf(fmaxf((0.0f - un) * inv, -10.0f), 4.0f);
        float dG = interp_tab(GI, ubx) - interp_tab(GI, lbx);
        float ua = 1.0f / (5.0f + 40.0f * dG);
        float dH = fmaxf(interp_tab(HI, ubx) - interp_tab(HI, lbx), 0.0f);
        float sa = sqrtf(3200.0f * dH * ua * ua * ua);
        float dg = interp_tab(GT, ubx) - interp_tab(GT, lbx);
        float ch = ua * ua * 40.0f * dg / (SQL * fmaxf(sa, 1e-9f));
        u_out[idx] = ua;
        s_out[idx] = sa;
        chi[idx] = ch;
    }
}

// ---------------- launcher ---------------------------------------------------
extern "C" void kernel_launch(void* const* d_in, const int* in_sizes, int n_in,
                              void* d_out, int out_size, void* d_ws, size_t ws_size,
                              hipStream_t stream) {
    (void)in_sizes; (void)n_in; (void)out_size; (void)ws_size;
    const float* u_in       = (const float*)d_in[0];
    const float* s_in       = (const float*)d_in[1];
    const float* rho_in     = (const float*)d_in[2];
    const float* u_ext      = (const float*)d_in[3];
    const float* s_ext      = (const float*)d_in[4];
    const float* W          = (const float*)d_in[5];
    const float* bvec       = (const float*)d_in[6];
    const float* W_ext      = (const float*)d_in[7];
    const float* b_ext      = (const float*)d_in[8];
    const float* w_mean     = (const float*)d_in[9];
    const float* b_mean     = (const float*)d_in[10];
    const float* w_mean_ext = (const float*)d_in[11];
    const float* b_mean_ext = (const float*)d_in[12];

    float* out_u   = (float*)d_out;
    float* out_s   = out_u + BB * NN;
    float* out_rho = out_s + BB * NN;
    unsigned short* Qh = (unsigned short*)out_rho;
    unsigned short* Ql = Qh + (size_t)BB * NN * NN;

    char* base = (char*)d_ws;
    size_t off = 0;
    auto alloc = [&](size_t bytes) -> char* {
        char* p = base + off;
        off += (bytes + 255) & ~(size_t)255;
        return p;
    };
    unsigned short* T1h = (unsigned short*)alloc((size_t)BB * NN * NN * 2);
    unsigned short* T1l = (unsigned short*)alloc((size_t)BB * NN * NN * 2);
    unsigned short* Wh  = (unsigned short*)alloc((size_t)NN * NN * 2);
    unsigned short* Wl  = (unsigned short*)alloc((size_t)NN * NN * 2);
    double* expP = (double*)alloc(TG * 8);
    double* expM = (double*)alloc(TG * 8);
    float* GTt   = (float*)alloc(TG * 4);
    float* GIt   = (float*)alloc(TG * 4);
    float* HIt   = (float*)alloc(TG * 4);
    float* u_e   = (float*)alloc(BB * NN * 4);
    float* s_e2  = (float*)alloc(BB * NN * 4);
    float* uA    = (float*)alloc(BB * NN * 4);
    float* uB2   = (float*)alloc(BB * NN * 4);
    float* sA    = (float*)alloc(BB * NN * 4);
    float* sB2   = (float*)alloc(BB * NN * 4);
    float* u_lin = (float*)alloc(BB * NN * 4);
    float* s_lin = (float*)alloc(BB * NN * 4);
    float* chi_  = (float*)alloc(BB * NN * 4);
    float* s_var = (float*)alloc(BB * NN * 4);

    // prologue
    k_exp<<<28, 256, 0, stream>>>(expP, expM);
    k_scan<<<1, 1024, 0, stream>>>(expP, expM, GTt, GIt, HIt);
    k_splitW<<<NN * NN / 256, 256, 0, stream>>>(W, Wh, Wl);
    k_splitQ<<<BB * NN * NN / 256, 256, 0, stream>>>(rho_in, s_in, Qh, Ql);
    k_ext_dots<<<BB * NN / 4, 256, 0, stream>>>(W_ext, b_ext, u_ext, s_ext, u_e, s_e2);
    k_ext_stats<<<2, 256, 0, stream>>>(u_e, s_e2, w_mean_ext, b_mean_ext);
    hipMemsetAsync(s_var, 0, BB * NN * 4, stream);

    const float* cu = u_in;

    for (int t = 0; t < SEQ; ++t) {
        // T1 = W @ Q + diag partials into s_var
        gemm_mfma<0, 0><<<512, 256, 0, stream>>>(
            Wh, Wl, 0L, Qh, Ql, (long)NN * NN, T1h, T1l, nullptr,
            W, s_var, nullptr, nullptr, nullptr);
        // u_lin = u @ W^T + b
        k_gemv<<<BB * NN / 4, 256, 0, stream>>>(W, bvec, cu, u_lin);
        // BN stats + apply + ext + activation (also s_lin from s_var, re-zero)
        float* nu = (t == SEQ - 1) ? out_u : ((t & 1) ? uA : uB2);
        float* ns = (t == SEQ - 1) ? out_s : ((t & 1) ? sA : sB2);
        k_bnact<<<2, 256, 0, stream>>>(
            u_lin, s_var, w_mean, b_mean, u_e, s_e2, GTt, GIt, HIt, nu, ns, chi_, s_lin);
        // C = T1 @ W^T with rho epilogue
        if (t < SEQ - 1) {
            gemm_mfma<1, 1><<<512, 256, 0, stream>>>(
                T1h, T1l, (long)NN * NN, Wh, Wl, 0L, Qh, Ql, nullptr,
                nullptr, nullptr, s_lin, chi_, ns);
        } else {
            gemm_mfma<2, 1><<<512, 256, 0, stream>>>(
                T1h, T1l, (long)NN * NN, Wh, Wl, 0L, nullptr, nullptr, out_rho,
                nullptr, nullptr, s_lin, chi_, nullptr);
        }
        cu = nu;
    }
}

// Round 5
// 799.252 us; speedup vs baseline: 1.1561x; 1.1561x over previous
//
#include <hip/hip_runtime.h>
#include <math.h>

// MomentLayerRecurrent — round 5 (round 4 + compile fix: param wm -> bn_w).
// (1) XOR fetch-swizzle kills 8-way LDS bank conflicts (GL16 slot is lane-fixed,
// so permute the fetched global chunk: chunk^(row&7); readers read slot
// gk^(row&7) -> 2-way max = free); (2) BK=64 halves barriers; (3) 2
// dispatches/step: u-GEMV folded into GEMM1 (xt==0 blocks, overlaps staging),
// BN+activation folded into GEMM2 prologue (recomputed per block, bitwise
// deterministic; diag blocks write u/s + zero ping-ponged s_var).

#define BB 32
#define NN 512
#define SEQ 8
#define TG 7001

typedef float f32x4 __attribute__((ext_vector_type(4)));
typedef short s16x8 __attribute__((ext_vector_type(8)));

#define GL16(g, l) __builtin_amdgcn_global_load_lds( \
    (const __attribute__((address_space(1))) void*)(g), \
    (__attribute__((address_space(3))) void*)(l), 16, 0, 0)

__device__ __forceinline__ unsigned short bf16_rne(float v) {
    unsigned u = __float_as_uint(v);
    u += 0x7FFFu + ((u >> 16) & 1u);
    return (unsigned short)(u >> 16);
}
__device__ __forceinline__ float bf16_f(unsigned short h) {
    return __uint_as_float(((unsigned)h) << 16);
}
__device__ __forceinline__ void split2(float v, unsigned short& h, unsigned short& l) {
    unsigned short hh = bf16_rne(v);
    h = hh;
    l = bf16_rne(v - bf16_f(hh));
}

__device__ __forceinline__ float interp_tab(const float* __restrict__ tab, float x) {
    float t = (x + 10.0f) * 500.0f;
    t = fminf(fmaxf(t, 0.0f), 7000.0f);
    int i0 = (int)t;
    if (i0 > 6999) i0 = 6999;
    float fr = t - (float)i0;
    float a = tab[i0];
    float b = tab[i0 + 1];
    return a + fr * (b - a);
}

// ---------------- exp precompute (parallel) ----------------------------------
__global__ void k_exp(double* __restrict__ expP, double* __restrict__ expM) {
    int k = blockIdx.x * 256 + threadIdx.x;
    if (k >= TG) return;
    double x = -10.0 + (14.0 / 7000.0) * k;
    expP[k] = exp(x * x);
    expM[k] = exp(-x * x);
}

// ---------------- chained cumtrapz scans, y staged in LDS --------------------
__device__ double blk_exscan(double part, double* wsum) {
    int t = threadIdx.x, lane = t & 63, wid = t >> 6;
    double run = part;
    #pragma unroll
    for (int off = 1; off < 64; off <<= 1) {
        double nv = __shfl_up(run, off);
        if (lane >= off) run += nv;
    }
    if (lane == 63) wsum[wid] = run;
    __syncthreads();
    if (t < 16) {
        double v = wsum[t];
        #pragma unroll
        for (int off = 1; off < 16; off <<= 1) {
            double nv = __shfl_up(v, off);
            if (lane >= off) v += nv;
        }
        wsum[t] = v;
    }
    __syncthreads();
    double base = (wid > 0) ? wsum[wid - 1] : 0.0;
    double ex = base + run - part;
    __syncthreads();
    return ex;
}

__global__ __launch_bounds__(1024)
void k_scan(const double* __restrict__ expP, const double* __restrict__ expM,
            float* __restrict__ GT, float* __restrict__ GI, float* __restrict__ HI) {
    __shared__ double ys[7008];
    __shared__ double wsum[16];
    const int t = threadIdx.x;
    const double dx = 14.0 / 7000.0;
    int k0 = t * 7, k1 = k0 + 7;
    if (k1 > TG) k1 = TG;
    if (k0 > TG) k0 = TG;
    int kls = (k0 < 1) ? 1 : k0;

    for (int k = k0; k < k1; ++k) ys[k] = expM[k];
    __syncthreads();

    double tmp[7];
    // phase 1: I = exp(-100)/20 + cumtrapz(expM); g = expP*I
    {
        double part = 0.0;
        for (int k = kls; k < k1; ++k) part += 0.5 * (ys[k - 1] + ys[k]) * dx;
        double run = blk_exscan(part, wsum) + exp(-100.0) / 20.0;
        int c = 0;
        for (int k = k0; k < k1; ++k) {
            if (k >= 1) run += 0.5 * (ys[k - 1] + ys[k]) * dx;
            tmp[c] = expP[k] * run;
            GT[k] = (float)tmp[c];
            ++c;
        }
        __syncthreads();
        c = 0;
        for (int k = k0; k < k1; ++k) ys[k] = tmp[c++];
        __syncthreads();
    }
    // phase 2: G = cumtrapz(g)
    {
        double part = 0.0;
        for (int k = kls; k < k1; ++k) part += 0.5 * (ys[k - 1] + ys[k]) * dx;
        double run = blk_exscan(part, wsum);
        for (int k = k0; k < k1; ++k) {
            if (k >= 1) run += 0.5 * (ys[k - 1] + ys[k]) * dx;
            GI[k] = (float)run;
        }
        __syncthreads();
    }
    // phase 3: E = cumtrapz(expM * g^2)
    {
        double part = 0.0;
        for (int k = kls; k < k1; ++k) {
            double ya = expM[k - 1] * ys[k - 1] * ys[k - 1];
            double yb = expM[k] * ys[k] * ys[k];
            part += 0.5 * (ya + yb) * dx;
        }
        double run = blk_exscan(part, wsum);
        int c = 0;
        for (int k = k0; k < k1; ++k) {
            if (k >= 1) {
                double ya = expM[k - 1] * ys[k - 1] * ys[k - 1];
                double yb = expM[k] * ys[k] * ys[k];
                run += 0.5 * (ya + yb) * dx;
            }
            tmp[c++] = run;
        }
        __syncthreads();
        c = 0;
        for (int k = k0; k < k1; ++k) ys[k] = tmp[c++];
        __syncthreads();
    }
    // phase 4: H = cumtrapz(expP * E)
    {
        double part = 0.0;
        for (int k = kls; k < k1; ++k)
            part += 0.5 * (expP[k - 1] * ys[k - 1] + expP[k] * ys[k]) * dx;
        double run = blk_exscan(part, wsum);
        for (int k = k0; k < k1; ++k) {
            if (k >= 1) run += 0.5 * (expP[k - 1] * ys[k - 1] + expP[k] * ys[k]) * dx;
            HI[k] = (float)run;
        }
    }
}

// ---------------- split kernels ----------------------------------------------
__global__ void k_splitW(const float* __restrict__ W,
                         unsigned short* __restrict__ Wh, unsigned short* __restrict__ Wl) {
    int idx = blockIdx.x * 256 + threadIdx.x;
    unsigned short h, l;
    split2(W[idx], h, l);
    Wh[idx] = h; Wl[idx] = l;
}

__global__ void k_splitQ(const float* __restrict__ rho, const float* __restrict__ s,
                         unsigned short* __restrict__ Qh, unsigned short* __restrict__ Ql) {
    size_t idx = (size_t)blockIdx.x * 256 + threadIdx.x;
    int b = (int)(idx >> 18);
    int i = (int)((idx >> 9) & 511);
    int j = (int)(idx & 511);
    float v = rho[idx] * s[b * NN + i] * s[b * NN + j];
    unsigned short h, l;
    split2(v, h, l);
    Qh[idx] = h; Ql[idx] = l;
}

// ---------------- fused MFMA GEMM step kernels -------------------------------
// 128x128 tile, BK=64, split-2 bf16 (3 products). XOR fetch-swizzle for
// conflict-free ds_read_b128. PHASE 0: T1 = W@Q, + diag(C) atomics into sv_a,
// + u_lin fold on xt==0 blocks. PHASE 1: C = T1@W^T with BN+activation
// recomputed in prologue; epilogue writes Q_next split-bf16; diag blocks write
// u/s_next and zero sv_b. PHASE 2: like 1 but writes fp32 rho.
template <int PHASE>
__global__ __launch_bounds__(256)
void gemm_step(const unsigned short* __restrict__ Ah, const unsigned short* __restrict__ Al,
               long aStride,
               const unsigned short* __restrict__ Bh, const unsigned short* __restrict__ Bl,
               long bStride,
               unsigned short* __restrict__ Oh, unsigned short* __restrict__ Ol,
               float* __restrict__ Of,
               const float* __restrict__ Wf, float* __restrict__ sv_a, float* __restrict__ sv_b,
               const float* __restrict__ u_prev, const float* __restrict__ bvec,
               float* __restrict__ u_lin,
               const float* __restrict__ bn_w, const float* __restrict__ bmv,
               const float* __restrict__ u_e, const float* __restrict__ s_e2,
               const float* __restrict__ GT, const float* __restrict__ GI,
               const float* __restrict__ HI,
               float* __restrict__ u_next, float* __restrict__ s_next) {
    __shared__ __align__(16) unsigned short As0[8192], As1[8192], Bs0[8192], Bs1[8192];
    __shared__ float slS[256], chS[256], snS[256];

    const int id = blockIdx.x;
    const int member = (id >> 3) & 3;
    const int g = (id & 7) | ((id >> 5) << 3);
    const int p = g & 3;
    const int b = g >> 2;
    const int xt = (PHASE == 0) ? p : member;   // swizzle: B-sharers (PHASE0) /
    const int yt = (PHASE == 0) ? member : p;   // A-sharers (PHASE1/2) same XCD
    const int i0 = yt * 128, j0 = xt * 128;
    const int tid = threadIdx.x;
    const int w = tid >> 6, lane = tid & 63;
    const int wqm = w >> 1, wqn = w & 1;

    const unsigned short* Abh = Ah + (size_t)b * aStride;
    const unsigned short* Abl = Al + (size_t)b * aStride;
    const unsigned short* Bbh = Bh + (size_t)b * bStride;
    const unsigned short* Bbl = Bl + (size_t)b * bStride;

    // per-lane swizzled fetch offset: row = lane>>3, chunk' = (lane&7)^(lane>>3)
    const size_t lgoff = ((size_t)(lane >> 3) * NN) + (size_t)(((lane & 7) ^ (lane >> 3)) << 3);

    auto stage = [&](int k0) {
        #pragma unroll
        for (int inst = 0; inst < 4; ++inst) {
            const int br = w * 32 + inst * 8;      // panel-local base row
            GL16(Abh + (size_t)(i0 + br) * NN + k0 + lgoff, As0 + br * 64);
            GL16(Abl + (size_t)(i0 + br) * NN + k0 + lgoff, As1 + br * 64);
            GL16(Bbh + (size_t)(j0 + br) * NN + k0 + lgoff, Bs0 + br * 64);
            GL16(Bbl + (size_t)(j0 + br) * NN + k0 + lgoff, Bs1 + br * 64);
        }
    };
    stage(0);

    // ---- overlapped prologue work (while staging(0) is in flight) ----
    if (PHASE == 0) {
        if (xt == 0) {   // u_lin fold: u_lin[b,row] = W[row,:].u_prev[b,:] + bvec
            const int row = i0 + (tid >> 1);
            const int half = tid & 1;
            const float4* wr = (const float4*)(Wf + (size_t)row * NN + half * 256);
            const float4* ur = (const float4*)(u_prev + b * NN + half * 256);
            float a0 = 0.f, a1 = 0.f, a2 = 0.f, a3 = 0.f;
            #pragma unroll 8
            for (int kk = 0; kk < 64; ++kk) {
                float4 wv = wr[kk], uv = ur[kk];
                a0 = fmaf(wv.x, uv.x, a0);
                a1 = fmaf(wv.y, uv.y, a1);
                a2 = fmaf(wv.z, uv.z, a2);
                a3 = fmaf(wv.w, uv.w, a3);
            }
            float au = (a0 + a1) + (a2 + a3);
            au += __shfl_xor(au, 1);
            if (half == 0) u_lin[b * NN + row] = au + bvec[row];
        }
    } else {
        // BN stats + activation for this block's 256 rows/cols (deterministic)
        const int ii = (tid < 128) ? (i0 + tid) : (j0 + tid - 128);
        float m = 0.0f;
        for (int bb = 0; bb < BB; ++bb) m += u_lin[bb * NN + ii];
        m *= (1.0f / BB);
        float v = 0.0f;
        for (int bb = 0; bb < BB; ++bb) {
            float d = u_lin[bb * NN + ii] - m;
            v = fmaf(d, d, v);
        }
        v *= (1.0f / BB);
        float f = bn_w[ii] / sqrtf(v + 1e-5f);
        const int idx = b * NN + ii;
        float s_l = sqrtf(fmaxf(sv_a[idx], 0.0f));
        float un = (u_lin[idx] - m) * f + bmv[ii] + u_e[idx];
        float sn = sqrtf(s_l * s_l * f * f + s_e2[idx]);
        const float SQL = 0.22360679774997896f;
        float ss = fmaxf(sn, 1e-6f);
        float inv = 1.0f / (ss * SQL);
        float ubx = fminf(fmaxf((1.0f - un) * inv, -10.0f), 4.0f);
        float lbx = fminf(fmaxf((0.0f - un) * inv, -10.0f), 4.0f);
        float dG = interp_tab(GI, ubx) - interp_tab(GI, lbx);
        float ua = 1.0f / (5.0f + 40.0f * dG);
        float dH = fmaxf(interp_tab(HI, ubx) - interp_tab(HI, lbx), 0.0f);
        float sa = sqrtf(3200.0f * dH * ua * ua * ua);
        float dg2 = interp_tab(GT, ubx) - interp_tab(GT, lbx);
        float ch = ua * ua * 40.0f * dg2 / (SQL * fmaxf(sa, 1e-9f));
        slS[tid] = s_l;
        chS[tid] = ch;
        snS[tid] = sa;
        if (i0 == j0 && tid < 128) {     // diag blocks: publish activation,
            u_next[idx] = ua;            // zero next step's s_var
            s_next[idx] = sa;
            sv_b[idx] = 0.0f;
        }
    }
    __syncthreads();   // staging(0) complete + slS visible

    f32x4 acc[4][4];
    #pragma unroll
    for (int m2 = 0; m2 < 4; ++m2)
        #pragma unroll
        for (int n2 = 0; n2 < 4; ++n2) acc[m2][n2] = (f32x4){0.f, 0.f, 0.f, 0.f};

    for (int k0 = 0;;) {
        #pragma unroll
        for (int s = 0; s < 2; ++s) {
            s16x8 ahf[4], alf[4], bhf[4], blf[4];
            #pragma unroll
            for (int t = 0; t < 4; ++t) {
                const int ra = wqm * 64 + t * 16 + (lane & 15);
                const int ao = ra * 64 + ((((lane >> 4) + s * 4) ^ (ra & 7)) << 3);
                ahf[t] = *reinterpret_cast<const s16x8*>(&As0[ao]);
                alf[t] = *reinterpret_cast<const s16x8*>(&As1[ao]);
                const int rb = wqn * 64 + t * 16 + (lane & 15);
                const int bo = rb * 64 + ((((lane >> 4) + s * 4) ^ (rb & 7)) << 3);
                bhf[t] = *reinterpret_cast<const s16x8*>(&Bs0[bo]);
                blf[t] = *reinterpret_cast<const s16x8*>(&Bs1[bo]);
            }
            #pragma unroll
            for (int m2 = 0; m2 < 4; ++m2)
                #pragma unroll
                for (int n2 = 0; n2 < 4; ++n2) {
                    acc[m2][n2] = __builtin_amdgcn_mfma_f32_16x16x32_bf16(ahf[m2], bhf[n2], acc[m2][n2], 0, 0, 0);
                    acc[m2][n2] = __builtin_amdgcn_mfma_f32_16x16x32_bf16(ahf[m2], blf[n2], acc[m2][n2], 0, 0, 0);
                    acc[m2][n2] = __builtin_amdgcn_mfma_f32_16x16x32_bf16(alf[m2], bhf[n2], acc[m2][n2], 0, 0, 0);
                }
        }
        k0 += 64;
        if (k0 >= NN) break;
        __syncthreads();
        stage(k0);
        __syncthreads();
    }

    // ---- epilogue — C/D layout: col = lane&15, row = (lane>>4)*4 + reg ----
    const size_t bofs = (size_t)b * NN * NN;

    if (PHASE == 0) {
        const int rb0 = i0 + wqm * 64 + (lane >> 4) * 4;
        const int cb0 = j0 + wqn * 64 + (lane & 15);
        // diag partials: dp = sum_n acc[m][n][r] * W[row, col_n], xor-reduced
        float dp[16];
        #pragma unroll
        for (int m2 = 0; m2 < 4; ++m2)
            #pragma unroll
            for (int r = 0; r < 4; ++r) {
                int row = rb0 + m2 * 16 + r;
                const float* wrow = Wf + ((size_t)row << 9) + cb0;
                float s = 0.0f;
                #pragma unroll
                for (int n2 = 0; n2 < 4; ++n2) s = fmaf(acc[m2][n2][r], wrow[n2 * 16], s);
                dp[m2 * 4 + r] = s;
            }
        #pragma unroll
        for (int k = 0; k < 16; ++k) {
            #pragma unroll
            for (int off = 1; off < 16; off <<= 1) dp[k] += __shfl_xor(dp[k], off);
        }
        if ((lane & 15) == 0) {
            #pragma unroll
            for (int k = 0; k < 16; ++k) {
                int row = rb0 + (k >> 2) * 16 + (k & 3);
                atomicAdd(&sv_a[b * NN + row], dp[k]);
            }
        }
        #pragma unroll
        for (int m2 = 0; m2 < 4; ++m2)
            #pragma unroll
            for (int n2 = 0; n2 < 4; ++n2) {
                int col = cb0 + n2 * 16;
                #pragma unroll
                for (int r = 0; r < 4; ++r) {
                    int row = rb0 + m2 * 16 + r;
                    size_t idx = bofs + ((size_t)row << 9) + col;
                    unsigned short h, l;
                    split2(acc[m2][n2][r], h, l);
                    Oh[idx] = h; Ol[idx] = l;
                }
            }
    } else {
        const int lrb = wqm * 64 + (lane >> 4) * 4;
        const int lcb = wqn * 64 + (lane & 15);
        #pragma unroll
        for (int m2 = 0; m2 < 4; ++m2)
            #pragma unroll
            for (int r = 0; r < 4; ++r) {
                const int lr = lrb + m2 * 16 + r;
                const float si = slS[lr], ci = chS[lr], qi = snS[lr];
                const int row = i0 + lr;
                #pragma unroll
                for (int n2 = 0; n2 < 4; ++n2) {
                    const int lc = lcb + n2 * 16;
                    const float sj = slS[128 + lc], cj = chS[128 + lc], qj = snS[128 + lc];
                    const int col = j0 + lc;
                    float denom = si * sj;
                    float rv = (denom > 1e-12f) ? (acc[m2][n2][r] / fmaxf(denom, 1e-12f)) : 0.0f;
                    rv *= ci * cj;
                    if (row == col) rv = 1.0f;
                    size_t idx = bofs + ((size_t)row << 9) + col;
                    if (PHASE == 1) {
                        unsigned short h, l;
                        split2(rv * qi * qj, h, l);
                        Oh[idx] = h; Ol[idx] = l;
                    } else {
                        Of[idx] = rv;
                    }
                }
            }
    }
}

// ---------------- external pathway -------------------------------------------
__global__ void k_ext_dots(const float* __restrict__ Wx, const float* __restrict__ bx,
                           const float* __restrict__ ux, const float* __restrict__ sx,
                           float* __restrict__ u_e, float* __restrict__ s_e2) {
    int gw = (blockIdx.x << 2) + (threadIdx.x >> 6);
    int lane = threadIdx.x & 63;
    int b = gw >> 9, i = gw & 511;
    const float* wr = Wx + (size_t)i * NN;
    const float* ub = ux + b * NN;
    const float* sb = sx + b * NN;
    float au = 0.0f, as2 = 0.0f;
    for (int j = lane; j < NN; j += 64) {
        float w = wr[j];
        float s = sb[j];
        au = fmaf(w, ub[j], au);
        as2 = fmaf(w * w, s * s, as2);
    }
    #pragma unroll
    for (int off = 32; off; off >>= 1) {
        au += __shfl_down(au, off);
        as2 += __shfl_down(as2, off);
    }
    if (lane == 0) {
        u_e[b * NN + i] = au + bx[i];
        s_e2[b * NN + i] = as2;
    }
}

__global__ void k_ext_stats(float* __restrict__ u_e, float* __restrict__ s_e2,
                            const float* __restrict__ wmx, const float* __restrict__ bmx) {
    int i = blockIdx.x * blockDim.x + threadIdx.x;
    if (i >= NN) return;
    float m = 0.0f;
    for (int b = 0; b < BB; ++b) m += u_e[b * NN + i];
    m *= (1.0f / BB);
    float v = 0.0f;
    for (int b = 0; b < BB; ++b) {
        float d = u_e[b * NN + i] - m;
        v = fmaf(d, d, v);
    }
    v *= (1.0f / BB);
    float f = wmx[i] / sqrtf(v + 1e-5f);
    float bm = bmx[i];
    for (int b = 0; b < BB; ++b) {
        u_e[b * NN + i] = (u_e[b * NN + i] - m) * f + bm;
        s_e2[b * NN + i] *= f * f;
    }
}

// ---------------- launcher ---------------------------------------------------
extern "C" void kernel_launch(void* const* d_in, const int* in_sizes, int n_in,
                              void* d_out, int out_size, void* d_ws, size_t ws_size,
                              hipStream_t stream) {
    (void)in_sizes; (void)n_in; (void)out_size; (void)ws_size;
    const float* u_in       = (const float*)d_in[0];
    const float* s_in       = (const float*)d_in[1];
    const float* rho_in     = (const float*)d_in[2];
    const float* u_ext      = (const float*)d_in[3];
    const float* s_ext      = (const float*)d_in[4];
    const float* W          = (const float*)d_in[5];
    const float* bvec       = (const float*)d_in[6];
    const float* W_ext      = (const float*)d_in[7];
    const float* b_ext      = (const float*)d_in[8];
    const float* w_mean     = (const float*)d_in[9];
    const float* b_mean     = (const float*)d_in[10];
    const float* w_mean_ext = (const float*)d_in[11];
    const float* b_mean_ext = (const float*)d_in[12];

    float* out_u   = (float*)d_out;
    float* out_s   = out_u + BB * NN;
    float* out_rho = out_s + BB * NN;
    unsigned short* Qh = (unsigned short*)out_rho;            // Q split lives in
    unsigned short* Ql = Qh + (size_t)BB * NN * NN;           // out_rho region

    char* base = (char*)d_ws;
    size_t off = 0;
    auto alloc = [&](size_t bytes) -> char* {
        char* ptr = base + off;
        off += (bytes + 255) & ~(size_t)255;
        return ptr;
    };
    unsigned short* T1h = (unsigned short*)alloc((size_t)BB * NN * NN * 2);
    unsigned short* T1l = (unsigned short*)alloc((size_t)BB * NN * NN * 2);
    unsigned short* Wh  = (unsigned short*)alloc((size_t)NN * NN * 2);
    unsigned short* Wl  = (unsigned short*)alloc((size_t)NN * NN * 2);
    double* expP = (double*)alloc(TG * 8);
    double* expM = (double*)alloc(TG * 8);
    float* GTt   = (float*)alloc(TG * 4);
    float* GIt   = (float*)alloc(TG * 4);
    float* HIt   = (float*)alloc(TG * 4);
    float* u_e   = (float*)alloc(BB * NN * 4);
    float* s_e2  = (float*)alloc(BB * NN * 4);
    float* uA    = (float*)alloc(BB * NN * 4);
    float* uB2   = (float*)alloc(BB * NN * 4);
    float* sA    = (float*)alloc(BB * NN * 4);
    float* sB2   = (float*)alloc(BB * NN * 4);
    float* u_lin = (float*)alloc(BB * NN * 4);
    float* sv0   = (float*)alloc(BB * NN * 4);
    float* sv1   = (float*)alloc(BB * NN * 4);

    // prologue
    k_exp<<<28, 256, 0, stream>>>(expP, expM);
    k_scan<<<1, 1024, 0, stream>>>(expP, expM, GTt, GIt, HIt);
    k_splitW<<<NN * NN / 256, 256, 0, stream>>>(W, Wh, Wl);
    k_splitQ<<<BB * NN * NN / 256, 256, 0, stream>>>(rho_in, s_in, Qh, Ql);
    k_ext_dots<<<BB * NN / 4, 256, 0, stream>>>(W_ext, b_ext, u_ext, s_ext, u_e, s_e2);
    k_ext_stats<<<2, 256, 0, stream>>>(u_e, s_e2, w_mean_ext, b_mean_ext);
    (void)hipMemsetAsync(sv0, 0, BB * NN * 4, stream);  // sv1 zeroed by step 0

    const float* cu = u_in;

    for (int t = 0; t < SEQ; ++t) {
        float* sva = (t & 1) ? sv1 : sv0;
        float* svb = (t & 1) ? sv0 : sv1;
        // T1 = W @ Q, diag atomics into sva, u_lin fold (xt==0 blocks)
        gemm_step<0><<<512, 256, 0, stream>>>(
            Wh, Wl, 0L, Qh, Ql, (long)NN * NN, T1h, T1l, nullptr,
            W, sva, nullptr, cu, bvec, u_lin,
            nullptr, nullptr, nullptr, nullptr, nullptr, nullptr, nullptr,
            nullptr, nullptr);
        float* nu = (t == SEQ - 1) ? out_u : ((t & 1) ? uA : uB2);
        float* ns = (t == SEQ - 1) ? out_s : ((t & 1) ? sA : sB2);
        // C = T1 @ W^T, BN+activation in prologue, rho epilogue
        if (t < SEQ - 1) {
            gemm_step<1><<<512, 256, 0, stream>>>(
                T1h, T1l, (long)NN * NN, Wh, Wl, 0L, Qh, Ql, nullptr,
                nullptr, sva, svb, nullptr, nullptr, u_lin,
                w_mean, b_mean, u_e, s_e2, GTt, GIt, HIt, nu, ns);
        } else {
            gemm_step<2><<<512, 256, 0, stream>>>(
                T1h, T1l, (long)NN * NN, Wh, Wl, 0L, nullptr, nullptr, out_rho,
                nullptr, sva, svb, nullptr, nullptr, u_lin,
                w_mean, b_mean, u_e, s_e2, GTt, GIt, HIt, nu, ns);
        }
        cu = nu;
    }
}

// Round 6
// 788.137 us; speedup vs baseline: 1.1724x; 1.0141x over previous
//
#include <hip/hip_runtime.h>
#include <math.h>

// MomentLayerRecurrent — round 6.
// vs round 5: (1) BK back to 32 (r5's BK=64 was the m132 trap: 64KB staging
// bursts with nothing to hide the barrier vmcnt(0) drain behind); (2) LDS
// ping-pong double buffer, ONE barrier per K-iter: stage(next) -> compute(cur)
// -> sync, so the drain overlaps 48 MFMA + 16 ds_read; (3) BK=32 XOR swizzle:
// fetch chunk' = (lane&3)^((lane>>3)&3), reader XOR folds to a lane constant
// -> immediate-offset ds_read_b128, uniform 8 lanes/4-bank group (b128 floor),
// 2-way max = free; (4) PHASE0 u-GEMV spread over all 16 blocks per batch.

#define BB 32
#define NN 512
#define SEQ 8
#define TG 7001

typedef float f32x4 __attribute__((ext_vector_type(4)));
typedef short s16x8 __attribute__((ext_vector_type(8)));

#define GL16(g, l) __builtin_amdgcn_global_load_lds( \
    (const __attribute__((address_space(1))) void*)(g), \
    (__attribute__((address_space(3))) void*)(l), 16, 0, 0)

__device__ __forceinline__ unsigned short bf16_rne(float v) {
    unsigned u = __float_as_uint(v);
    u += 0x7FFFu + ((u >> 16) & 1u);
    return (unsigned short)(u >> 16);
}
__device__ __forceinline__ float bf16_f(unsigned short h) {
    return __uint_as_float(((unsigned)h) << 16);
}
__device__ __forceinline__ void split2(float v, unsigned short& h, unsigned short& l) {
    unsigned short hh = bf16_rne(v);
    h = hh;
    l = bf16_rne(v - bf16_f(hh));
}

__device__ __forceinline__ float interp_tab(const float* __restrict__ tab, float x) {
    float t = (x + 10.0f) * 500.0f;
    t = fminf(fmaxf(t, 0.0f), 7000.0f);
    int i0 = (int)t;
    if (i0 > 6999) i0 = 6999;
    float fr = t - (float)i0;
    float a = tab[i0];
    float b = tab[i0 + 1];
    return a + fr * (b - a);
}

// ---------------- exp precompute (parallel) ----------------------------------
__global__ void k_exp(double* __restrict__ expP, double* __restrict__ expM) {
    int k = blockIdx.x * 256 + threadIdx.x;
    if (k >= TG) return;
    double x = -10.0 + (14.0 / 7000.0) * k;
    expP[k] = exp(x * x);
    expM[k] = exp(-x * x);
}

// ---------------- chained cumtrapz scans, y staged in LDS --------------------
__device__ double blk_exscan(double part, double* wsum) {
    int t = threadIdx.x, lane = t & 63, wid = t >> 6;
    double run = part;
    #pragma unroll
    for (int off = 1; off < 64; off <<= 1) {
        double nv = __shfl_up(run, off);
        if (lane >= off) run += nv;
    }
    if (lane == 63) wsum[wid] = run;
    __syncthreads();
    if (t < 16) {
        double v = wsum[t];
        #pragma unroll
        for (int off = 1; off < 16; off <<= 1) {
            double nv = __shfl_up(v, off);
            if (lane >= off) v += nv;
        }
        wsum[t] = v;
    }
    __syncthreads();
    double base = (wid > 0) ? wsum[wid - 1] : 0.0;
    double ex = base + run - part;
    __syncthreads();
    return ex;
}

__global__ __launch_bounds__(1024)
void k_scan(const double* __restrict__ expP, const double* __restrict__ expM,
            float* __restrict__ GT, float* __restrict__ GI, float* __restrict__ HI) {
    __shared__ double ys[7008];
    __shared__ double wsum[16];
    const int t = threadIdx.x;
    const double dx = 14.0 / 7000.0;
    int k0 = t * 7, k1 = k0 + 7;
    if (k1 > TG) k1 = TG;
    if (k0 > TG) k0 = TG;
    int kls = (k0 < 1) ? 1 : k0;

    for (int k = k0; k < k1; ++k) ys[k] = expM[k];
    __syncthreads();

    double tmp[7];
    // phase 1: I = exp(-100)/20 + cumtrapz(expM); g = expP*I
    {
        double part = 0.0;
        for (int k = kls; k < k1; ++k) part += 0.5 * (ys[k - 1] + ys[k]) * dx;
        double run = blk_exscan(part, wsum) + exp(-100.0) / 20.0;
        int c = 0;
        for (int k = k0; k < k1; ++k) {
            if (k >= 1) run += 0.5 * (ys[k - 1] + ys[k]) * dx;
            tmp[c] = expP[k] * run;
            GT[k] = (float)tmp[c];
            ++c;
        }
        __syncthreads();
        c = 0;
        for (int k = k0; k < k1; ++k) ys[k] = tmp[c++];
        __syncthreads();
    }
    // phase 2: G = cumtrapz(g)
    {
        double part = 0.0;
        for (int k = kls; k < k1; ++k) part += 0.5 * (ys[k - 1] + ys[k]) * dx;
        double run = blk_exscan(part, wsum);
        for (int k = k0; k < k1; ++k) {
            if (k >= 1) run += 0.5 * (ys[k - 1] + ys[k]) * dx;
            GI[k] = (float)run;
        }
        __syncthreads();
    }
    // phase 3: E = cumtrapz(expM * g^2)
    {
        double part = 0.0;
        for (int k = kls; k < k1; ++k) {
            double ya = expM[k - 1] * ys[k - 1] * ys[k - 1];
            double yb = expM[k] * ys[k] * ys[k];
            part += 0.5 * (ya + yb) * dx;
        }
        double run = blk_exscan(part, wsum);
        int c = 0;
        for (int k = k0; k < k1; ++k) {
            if (k >= 1) {
                double ya = expM[k - 1] * ys[k - 1] * ys[k - 1];
                double yb = expM[k] * ys[k] * ys[k];
                run += 0.5 * (ya + yb) * dx;
            }
            tmp[c++] = run;
        }
        __syncthreads();
        c = 0;
        for (int k = k0; k < k1; ++k) ys[k] = tmp[c++];
        __syncthreads();
    }
    // phase 4: H = cumtrapz(expP * E)
    {
        double part = 0.0;
        for (int k = kls; k < k1; ++k)
            part += 0.5 * (expP[k - 1] * ys[k - 1] + expP[k] * ys[k]) * dx;
        double run = blk_exscan(part, wsum);
        for (int k = k0; k < k1; ++k) {
            if (k >= 1) run += 0.5 * (expP[k - 1] * ys[k - 1] + expP[k] * ys[k]) * dx;
            HI[k] = (float)run;
        }
    }
}

// ---------------- split kernels ----------------------------------------------
__global__ void k_splitW(const float* __restrict__ W,
                         unsigned short* __restrict__ Wh, unsigned short* __restrict__ Wl) {
    int idx = blockIdx.x * 256 + threadIdx.x;
    unsigned short h, l;
    split2(W[idx], h, l);
    Wh[idx] = h; Wl[idx] = l;
}

__global__ void k_splitQ(const float* __restrict__ rho, const float* __restrict__ s,
                         unsigned short* __restrict__ Qh, unsigned short* __restrict__ Ql) {
    size_t idx = (size_t)blockIdx.x * 256 + threadIdx.x;
    int b = (int)(idx >> 18);
    int i = (int)((idx >> 9) & 511);
    int j = (int)(idx & 511);
    float v = rho[idx] * s[b * NN + i] * s[b * NN + j];
    unsigned short h, l;
    split2(v, h, l);
    Qh[idx] = h; Ql[idx] = l;
}

// ---------------- fused MFMA GEMM step kernels -------------------------------
// 128x128 tile, BK=32, split-2 bf16 (3 products), LDS ping-pong (1 barrier/iter).
// PHASE 0: T1 = W@Q, diag(C) atomics into sv_a, balanced u_lin fold (32 rows/blk).
// PHASE 1: C = T1@W^T, BN+activation in prologue; epilogue writes Q_next split.
// PHASE 2: like 1 but writes fp32 rho.
template <int PHASE>
__global__ __launch_bounds__(256)
void gemm_step(const unsigned short* __restrict__ Ah, const unsigned short* __restrict__ Al,
               long aStride,
               const unsigned short* __restrict__ Bh, const unsigned short* __restrict__ Bl,
               long bStride,
               unsigned short* __restrict__ Oh, unsigned short* __restrict__ Ol,
               float* __restrict__ Of,
               const float* __restrict__ Wf, float* __restrict__ sv_a, float* __restrict__ sv_b,
               const float* __restrict__ u_prev, const float* __restrict__ bvec,
               float* __restrict__ u_lin,
               const float* __restrict__ bn_w, const float* __restrict__ bmv,
               const float* __restrict__ u_e, const float* __restrict__ s_e2,
               const float* __restrict__ GT, const float* __restrict__ GI,
               const float* __restrict__ HI,
               float* __restrict__ u_next, float* __restrict__ s_next) {
    // double-buffered: [2][128 rows][32 ushorts]
    __shared__ __align__(16) unsigned short As0[8192], As1[8192], Bs0[8192], Bs1[8192];
    __shared__ float slS[256], chS[256], snS[256];

    const int id = blockIdx.x;
    const int member = (id >> 3) & 3;
    const int g = (id & 7) | ((id >> 5) << 3);
    const int p = g & 3;
    const int b = g >> 2;
    const int xt = (PHASE == 0) ? p : member;   // B-sharers (PHASE0) /
    const int yt = (PHASE == 0) ? member : p;   // A-sharers (PHASE1/2) same XCD
    const int i0 = yt * 128, j0 = xt * 128;
    const int tid = threadIdx.x;
    const int w = tid >> 6, lane = tid & 63;
    const int wqm = w >> 1, wqn = w & 1;
    const int kg = lane >> 4;

    const unsigned short* Abh = Ah + (size_t)b * aStride;
    const unsigned short* Abl = Al + (size_t)b * aStride;
    const unsigned short* Bbh = Bh + (size_t)b * bStride;
    const unsigned short* Bbl = Bl + (size_t)b * bStride;

    // fetch: 16 rows x 4 chunks per GL16; row = lane>>2, chunk' = (lane&3)^((lane>>3)&3)
    const size_t lgoff = ((size_t)(lane >> 2) * NN) + (size_t)((((lane & 3) ^ ((lane >> 3) & 3)) << 3));
    // reader: slot chunk = kg ^ ((r>>1)&3) -> lane-constant (see derivation)
    const int cxor = ((kg ^ (((lane & 15) >> 1) & 3)) << 3);

    auto stage = [&](int pp, int k0) {
        const int bufo = pp * 4096;
        #pragma unroll
        for (int inst = 0; inst < 2; ++inst) {
            const int br = w * 32 + inst * 16;   // wave-uniform LDS row base
            GL16(Abh + (size_t)(i0 + br) * NN + k0 + lgoff, As0 + bufo + br * 32);
            GL16(Abl + (size_t)(i0 + br) * NN + k0 + lgoff, As1 + bufo + br * 32);
            GL16(Bbh + (size_t)(j0 + br) * NN + k0 + lgoff, Bs0 + bufo + br * 32);
            GL16(Bbl + (size_t)(j0 + br) * NN + k0 + lgoff, Bs1 + bufo + br * 32);
        }
    };
    stage(0, 0);

    // ---- overlapped prologue work (while staging(0) is in flight) ----
    if (PHASE == 0) {
        // balanced u-GEMV: each of the 16 blocks of batch b does 32 rows
        const int tile16 = yt * 4 + xt;
        const int row = tile16 * 32 + (tid >> 3);
        const int seg = tid & 7;
        const float4* wr = (const float4*)(Wf + (size_t)row * NN + seg * 64);
        const float4* ur = (const float4*)(u_prev + b * NN + seg * 64);
        float a0 = 0.f, a1 = 0.f, a2 = 0.f, a3 = 0.f;
        #pragma unroll
        for (int kk = 0; kk < 16; ++kk) {
            float4 wv = wr[kk], uv = ur[kk];
            a0 = fmaf(wv.x, uv.x, a0);
            a1 = fmaf(wv.y, uv.y, a1);
            a2 = fmaf(wv.z, uv.z, a2);
            a3 = fmaf(wv.w, uv.w, a3);
        }
        float au = (a0 + a1) + (a2 + a3);
        au += __shfl_xor(au, 1);
        au += __shfl_xor(au, 2);
        au += __shfl_xor(au, 4);
        if (seg == 0) u_lin[b * NN + row] = au + bvec[row];
    } else {
        // BN stats + activation for this block's 256 rows/cols (deterministic)
        const int ii = (tid < 128) ? (i0 + tid) : (j0 + tid - 128);
        float m = 0.0f;
        for (int bb = 0; bb < BB; ++bb) m += u_lin[bb * NN + ii];
        m *= (1.0f / BB);
        float v = 0.0f;
        for (int bb = 0; bb < BB; ++bb) {
            float d = u_lin[bb * NN + ii] - m;
            v = fmaf(d, d, v);
        }
        v *= (1.0f / BB);
        float f = bn_w[ii] / sqrtf(v + 1e-5f);
        const int idx = b * NN + ii;
        float s_l = sqrtf(fmaxf(sv_a[idx], 0.0f));
        float un = (u_lin[idx] - m) * f + bmv[ii] + u_e[idx];
        float sn = sqrtf(s_l * s_l * f * f + s_e2[idx]);
        const float SQL = 0.22360679774997896f;
        float ss = fmaxf(sn, 1e-6f);
        float inv = 1.0f / (ss * SQL);
        float ubx = fminf(fmaxf((1.0f - un) * inv, -10.0f), 4.0f);
        float lbx = fminf(fmaxf((0.0f - un) * inv, -10.0f), 4.0f);
        float dG = interp_tab(GI, ubx) - interp_tab(GI, lbx);
        float ua = 1.0f / (5.0f + 40.0f * dG);
        float dH = fmaxf(interp_tab(HI, ubx) - interp_tab(HI, lbx), 0.0f);
        float sa = sqrtf(3200.0f * dH * ua * ua * ua);
        float dg2 = interp_tab(GT, ubx) - interp_tab(GT, lbx);
        float ch = ua * ua * 40.0f * dg2 / (SQL * fmaxf(sa, 1e-9f));
        slS[tid] = s_l;
        chS[tid] = ch;
        snS[tid] = sa;
        if (i0 == j0 && tid < 128) {     // diag blocks: publish activation,
            u_next[idx] = ua;            // zero next step's s_var
            s_next[idx] = sa;
            sv_b[idx] = 0.0f;
        }
    }
    __syncthreads();   // staging(0) complete + slS visible

    f32x4 acc[4][4];
    #pragma unroll
    for (int m2 = 0; m2 < 4; ++m2)
        #pragma unroll
        for (int n2 = 0; n2 < 4; ++n2) acc[m2][n2] = (f32x4){0.f, 0.f, 0.f, 0.f};

    // ping-pong K loop: stage(next) -> compute(cur) -> one barrier
    for (int it = 0; it < 16; ++it) {
        if (it < 15) stage((it + 1) & 1, (it + 1) * 32);
        const int bufo = (it & 1) * 4096;
        s16x8 ahf[4], alf[4], bhf[4], blf[4];
        #pragma unroll
        for (int t = 0; t < 4; ++t) {
            const int ao = bufo + (wqm * 64 + t * 16 + (lane & 15)) * 32 + cxor;
            ahf[t] = *reinterpret_cast<const s16x8*>(&As0[ao]);
            alf[t] = *reinterpret_cast<const s16x8*>(&As1[ao]);
            const int bo = bufo + (wqn * 64 + t * 16 + (lane & 15)) * 32 + cxor;
            bhf[t] = *reinterpret_cast<const s16x8*>(&Bs0[bo]);
            blf[t] = *reinterpret_cast<const s16x8*>(&Bs1[bo]);
        }
        #pragma unroll
        for (int m2 = 0; m2 < 4; ++m2)
            #pragma unroll
            for (int n2 = 0; n2 < 4; ++n2) {
                acc[m2][n2] = __builtin_amdgcn_mfma_f32_16x16x32_bf16(ahf[m2], bhf[n2], acc[m2][n2], 0, 0, 0);
                acc[m2][n2] = __builtin_amdgcn_mfma_f32_16x16x32_bf16(ahf[m2], blf[n2], acc[m2][n2], 0, 0, 0);
                acc[m2][n2] = __builtin_amdgcn_mfma_f32_16x16x32_bf16(alf[m2], bhf[n2], acc[m2][n2], 0, 0, 0);
            }
        __syncthreads();
    }

    // ---- epilogue — C/D layout: col = lane&15, row = (lane>>4)*4 + reg ----
    const size_t bofs = (size_t)b * NN * NN;

    if (PHASE == 0) {
        const int rb0 = i0 + wqm * 64 + (lane >> 4) * 4;
        const int cb0 = j0 + wqn * 64 + (lane & 15);
        // diag partials: dp = sum_n acc[m][n][r] * W[row, col_n], xor-reduced
        float dp[16];
        #pragma unroll
        for (int m2 = 0; m2 < 4; ++m2)
            #pragma unroll
            for (int r = 0; r < 4; ++r) {
                int row = rb0 + m2 * 16 + r;
                const float* wrow = Wf + ((size_t)row << 9) + cb0;
                float s = 0.0f;
                #pragma unroll
                for (int n2 = 0; n2 < 4; ++n2) s = fmaf(acc[m2][n2][r], wrow[n2 * 16], s);
                dp[m2 * 4 + r] = s;
            }
        #pragma unroll
        for (int k = 0; k < 16; ++k) {
            #pragma unroll
            for (int off = 1; off < 16; off <<= 1) dp[k] += __shfl_xor(dp[k], off);
        }
        if ((lane & 15) == 0) {
            #pragma unroll
            for (int k = 0; k < 16; ++k) {
                int row = rb0 + (k >> 2) * 16 + (k & 3);
                atomicAdd(&sv_a[b * NN + row], dp[k]);
            }
        }
        #pragma unroll
        for (int m2 = 0; m2 < 4; ++m2)
            #pragma unroll
            for (int n2 = 0; n2 < 4; ++n2) {
                int col = cb0 + n2 * 16;
                #pragma unroll
                for (int r = 0; r < 4; ++r) {
                    int row = rb0 + m2 * 16 + r;
                    size_t idx = bofs + ((size_t)row << 9) + col;
                    unsigned short h, l;
                    split2(acc[m2][n2][r], h, l);
                    Oh[idx] = h; Ol[idx] = l;
                }
            }
    } else {
        const int lrb = wqm * 64 + (lane >> 4) * 4;
        const int lcb = wqn * 64 + (lane & 15);
        #pragma unroll
        for (int m2 = 0; m2 < 4; ++m2)
            #pragma unroll
            for (int r = 0; r < 4; ++r) {
                const int lr = lrb + m2 * 16 + r;
                const float si = slS[lr], ci = chS[lr], qi = snS[lr];
                const int row = i0 + lr;
                #pragma unroll
                for (int n2 = 0; n2 < 4; ++n2) {
                    const int lc = lcb + n2 * 16;
                    const float sj = slS[128 + lc], cj = chS[128 + lc], qj = snS[128 + lc];
                    const int col = j0 + lc;
                    float denom = si * sj;
                    float rv = (denom > 1e-12f) ? (acc[m2][n2][r] / fmaxf(denom, 1e-12f)) : 0.0f;
                    rv *= ci * cj;
                    if (row == col) rv = 1.0f;
                    size_t idx = bofs + ((size_t)row << 9) + col;
                    if (PHASE == 1) {
                        unsigned short h, l;
                        split2(rv * qi * qj, h, l);
                        Oh[idx] = h; Ol[idx] = l;
                    } else {
                        Of[idx] = rv;
                    }
                }
            }
    }
}

// ---------------- external pathway -------------------------------------------
__global__ void k_ext_dots(const float* __restrict__ Wx, const float* __restrict__ bx,
                           const float* __restrict__ ux, const float* __restrict__ sx,
                           float* __restrict__ u_e, float* __restrict__ s_e2) {
    int gw = (blockIdx.x << 2) + (threadIdx.x >> 6);
    int lane = threadIdx.x & 63;
    int b = gw >> 9, i = gw & 511;
    const float* wr = Wx + (size_t)i * NN;
    const float* ub = ux + b * NN;
    const float* sb = sx + b * NN;
    float au = 0.0f, as2 = 0.0f;
    for (int j = lane; j < NN; j += 64) {
        float w = wr[j];
        float s = sb[j];
        au = fmaf(w, ub[j], au);
        as2 = fmaf(w * w, s * s, as2);
    }
    #pragma unroll
    for (int off = 32; off; off >>= 1) {
        au += __shfl_down(au, off);
        as2 += __shfl_down(as2, off);
    }
    if (lane == 0) {
        u_e[b * NN + i] = au + bx[i];
        s_e2[b * NN + i] = as2;
    }
}

__global__ void k_ext_stats(float* __restrict__ u_e, float* __restrict__ s_e2,
                            const float* __restrict__ wmx, const float* __restrict__ bmx) {
    int i = blockIdx.x * blockDim.x + threadIdx.x;
    if (i >= NN) return;
    float m = 0.0f;
    for (int b = 0; b < BB; ++b) m += u_e[b * NN + i];
    m *= (1.0f / BB);
    float v = 0.0f;
    for (int b = 0; b < BB; ++b) {
        float d = u_e[b * NN + i] - m;
        v = fmaf(d, d, v);
    }
    v *= (1.0f / BB);
    float f = wmx[i] / sqrtf(v + 1e-5f);
    float bm = bmx[i];
    for (int b = 0; b < BB; ++b) {
        u_e[b * NN + i] = (u_e[b * NN + i] - m) * f + bm;
        s_e2[b * NN + i] *= f * f;
    }
}

// ---------------- launcher ---------------------------------------------------
extern "C" void kernel_launch(void* const* d_in, const int* in_sizes, int n_in,
                              void* d_out, int out_size, void* d_ws, size_t ws_size,
                              hipStream_t stream) {
    (void)in_sizes; (void)n_in; (void)out_size; (void)ws_size;
    const float* u_in       = (const float*)d_in[0];
    const float* s_in       = (const float*)d_in[1];
    const float* rho_in     = (const float*)d_in[2];
    const float* u_ext      = (const float*)d_in[3];
    const float* s_ext      = (const float*)d_in[4];
    const float* W          = (const float*)d_in[5];
    const float* bvec       = (const float*)d_in[6];
    const float* W_ext      = (const float*)d_in[7];
    const float* b_ext      = (const float*)d_in[8];
    const float* w_mean     = (const float*)d_in[9];
    const float* b_mean     = (const float*)d_in[10];
    const float* w_mean_ext = (const float*)d_in[11];
    const float* b_mean_ext = (const float*)d_in[12];

    float* out_u   = (float*)d_out;
    float* out_s   = out_u + BB * NN;
    float* out_rho = out_s + BB * NN;
    unsigned short* Qh = (unsigned short*)out_rho;            // Q split lives in
    unsigned short* Ql = Qh + (size_t)BB * NN * NN;           // out_rho region

    char* base = (char*)d_ws;
    size_t off = 0;
    auto alloc = [&](size_t bytes) -> char* {
        char* ptr = base + off;
        off += (bytes + 255) & ~(size_t)255;
        return ptr;
    };
    unsigned short* T1h = (unsigned short*)alloc((size_t)BB * NN * NN * 2);
    unsigned short* T1l = (unsigned short*)alloc((size_t)BB * NN * NN * 2);
    unsigned short* Wh  = (unsigned short*)alloc((size_t)NN * NN * 2);
    unsigned short* Wl  = (unsigned short*)alloc((size_t)NN * NN * 2);
    double* expP = (double*)alloc(TG * 8);
    double* expM = (double*)alloc(TG * 8);
    float* GTt   = (float*)alloc(TG * 4);
    float* GIt   = (float*)alloc(TG * 4);
    float* HIt   = (float*)alloc(TG * 4);
    float* u_e   = (float*)alloc(BB * NN * 4);
    float* s_e2  = (float*)alloc(BB * NN * 4);
    float* uA    = (float*)alloc(BB * NN * 4);
    float* uB2   = (float*)alloc(BB * NN * 4);
    float* sA    = (float*)alloc(BB * NN * 4);
    float* sB2   = (float*)alloc(BB * NN * 4);
    float* u_lin = (float*)alloc(BB * NN * 4);
    float* sv0   = (float*)alloc(BB * NN * 4);
    float* sv1   = (float*)alloc(BB * NN * 4);

    // prologue
    k_exp<<<28, 256, 0, stream>>>(expP, expM);
    k_scan<<<1, 1024, 0, stream>>>(expP, expM, GTt, GIt, HIt);
    k_splitW<<<NN * NN / 256, 256, 0, stream>>>(W, Wh, Wl);
    k_splitQ<<<BB * NN * NN / 256, 256, 0, stream>>>(rho_in, s_in, Qh, Ql);
    k_ext_dots<<<BB * NN / 4, 256, 0, stream>>>(W_ext, b_ext, u_ext, s_ext, u_e, s_e2);
    k_ext_stats<<<2, 256, 0, stream>>>(u_e, s_e2, w_mean_ext, b_mean_ext);
    (void)hipMemsetAsync(sv0, 0, BB * NN * 4, stream);  // sv1 zeroed by step 0

    const float* cu = u_in;

    for (int t = 0; t < SEQ; ++t) {
        float* sva = (t & 1) ? sv1 : sv0;
        float* svb = (t & 1) ? sv0 : sv1;
        // T1 = W @ Q, diag atomics into sva, balanced u_lin fold
        gemm_step<0><<<512, 256, 0, stream>>>(
            Wh, Wl, 0L, Qh, Ql, (long)NN * NN, T1h, T1l, nullptr,
            W, sva, nullptr, cu, bvec, u_lin,
            nullptr, nullptr, nullptr, nullptr, nullptr, nullptr, nullptr,
            nullptr, nullptr);
        float* nu = (t == SEQ - 1) ? out_u : ((t & 1) ? uA : uB2);
        float* ns = (t == SEQ - 1) ? out_s : ((t & 1) ? sA : sB2);
        // C = T1 @ W^T, BN+activation in prologue, rho epilogue
        if (t < SEQ - 1) {
            gemm_step<1><<<512, 256, 0, stream>>>(
                T1h, T1l, (long)NN * NN, Wh, Wl, 0L, Qh, Ql, nullptr,
                nullptr, sva, svb, nullptr, nullptr, u_lin,
                w_mean, b_mean, u_e, s_e2, GTt, GIt, HIt, nu, ns);
        } else {
            gemm_step<2><<<512, 256, 0, stream>>>(
                T1h, T1l, (long)NN * NN, Wh, Wl, 0L, nullptr, nullptr, out_rho,
                nullptr, sva, svb, nullptr, nullptr, u_lin,
                w_mean, b_mean, u_e, s_e2, GTt, GIt, HIt, nu, ns);
        }
        cu = nu;
    }
}